// Round 16
// baseline (475.873 us; speedup 1.0000x reference)
//
#include <hip/hip_runtime.h>

#define NEG_SLOPE 0.2f

// round-to-nearest-even fp32 -> bf16 bits
static __device__ __forceinline__ unsigned short f2bf(float f) {
    unsigned u = __float_as_uint(f);
    u += 0x7fffu + ((u >> 16) & 1u);
    return (unsigned short)(u >> 16);
}

// K-1: weight prep (no data deps): P1[d][h] at cst[16..80), P2[d] at cst[80..96)
__global__ void k_prep0(const float* __restrict__ We1, const float* __restrict__ ae1,
                        const float* __restrict__ We2, const float* __restrict__ ae2,
                        float* __restrict__ cst) {
    int t = threadIdx.x;
    if (t < 64) {
        int d = t >> 2, h = t & 3;
        float s = 0.f;
        for (int c = 0; c < 32; ++c) s += We1[d * 128 + h * 32 + c] * ae1[h * 32 + c];
        cst[16 + t] = s;
    } else if (t < 80) {
        int d = t - 64;
        float s = 0.f;
        for (int c = 0; c < 32; ++c) s += We2[d * 32 + c] * ae2[c];
        cst[80 + d] = s;
    }
}

// K0a: dst-degree histogram ONLY (one thread per edge, one atomic).
// Split from the streaming dot kernel: fusing them regressed 73->104 us at high
// occupancy (round-15: atomic contention vs streaming want opposite grids).
__global__ void k_deg(const int* __restrict__ ei, int* __restrict__ cursor, int E) {
    int e = blockIdx.x * blockDim.x + threadIdx.x;
    if (e < E) atomicAdd(&cursor[ei[E + e]], 1);
}

// K0b: pure streaming: edge_attr column sums + edot1/edot2 precompute. No
// per-edge atomics -> scales with occupancy (2048 blocks).
__global__ void k_edot(const float* __restrict__ ea, float* __restrict__ cst,
                       float4* __restrict__ edot1, float* __restrict__ edot2, int E) {
    float loc[16];
#pragma unroll
    for (int d = 0; d < 16; ++d) loc[d] = 0.f;
    int stride = gridDim.x * blockDim.x;
    for (int e = blockIdx.x * blockDim.x + threadIdx.x; e < E; e += stride) {
        const float4* eav = (const float4*)&ea[(size_t)e * 16];
        float d0 = 0.f, d1 = 0.f, d2 = 0.f, d3 = 0.f, dd = 0.f;
#pragma unroll
        for (int q = 0; q < 4; ++q) {
            float4 a = eav[q];
            loc[q * 4 + 0] += a.x; loc[q * 4 + 1] += a.y;
            loc[q * 4 + 2] += a.z; loc[q * 4 + 3] += a.w;
            d0 += a.x * cst[16 + (q * 4 + 0) * 4 + 0] + a.y * cst[16 + (q * 4 + 1) * 4 + 0]
                + a.z * cst[16 + (q * 4 + 2) * 4 + 0] + a.w * cst[16 + (q * 4 + 3) * 4 + 0];
            d1 += a.x * cst[16 + (q * 4 + 0) * 4 + 1] + a.y * cst[16 + (q * 4 + 1) * 4 + 1]
                + a.z * cst[16 + (q * 4 + 2) * 4 + 1] + a.w * cst[16 + (q * 4 + 3) * 4 + 1];
            d2 += a.x * cst[16 + (q * 4 + 0) * 4 + 2] + a.y * cst[16 + (q * 4 + 1) * 4 + 2]
                + a.z * cst[16 + (q * 4 + 2) * 4 + 2] + a.w * cst[16 + (q * 4 + 3) * 4 + 2];
            d3 += a.x * cst[16 + (q * 4 + 0) * 4 + 3] + a.y * cst[16 + (q * 4 + 1) * 4 + 3]
                + a.z * cst[16 + (q * 4 + 2) * 4 + 3] + a.w * cst[16 + (q * 4 + 3) * 4 + 3];
            dd += a.x * cst[80 + q * 4 + 0] + a.y * cst[80 + q * 4 + 1]
                + a.z * cst[80 + q * 4 + 2] + a.w * cst[80 + q * 4 + 3];
        }
        edot1[e] = make_float4(d0, d1, d2, d3);
        edot2[e] = dd;
    }
    __shared__ float sh[16];
    if (threadIdx.x < 16) sh[threadIdx.x] = 0.f;
    __syncthreads();
#pragma unroll
    for (int d = 0; d < 16; ++d) atomicAdd(&sh[d], loc[d]);
    __syncthreads();
    if (threadIdx.x < 16) atomicAdd(&cst[threadIdx.x], sh[threadIdx.x]);
}

// scan phase 1: block-local exclusive scan of (deg+1) [+1 = self-loop]
__global__ void k_scan1(const int* __restrict__ deg, int* __restrict__ excl,
                        int* __restrict__ bsum, int N) {
    __shared__ int sh[1024];
    const int t = threadIdx.x;
    const int i = blockIdx.x * 1024 + t;
    int v = (i < N) ? deg[i] + 1 : 0;
    sh[t] = v;
    __syncthreads();
    for (int off = 1; off < 1024; off <<= 1) {
        int add = (t >= off) ? sh[t - off] : 0;
        __syncthreads();
        sh[t] += add;
        __syncthreads();
    }
    if (i < N) excl[i] = sh[t] - v;
    if (t == 1023) bsum[blockIdx.x] = sh[1023];
}

// fused: block 0 = exclusive scan of bsum; block 1 = e_mean + self-loop dots
// cst: [0..16) e_mean, [16..80) P1, [80..96) P2, [96..100) aloop1, [100] aloop2
__global__ void k_mid(int* __restrict__ bsum, int nb, float* __restrict__ cst, float Ef) {
    __shared__ int sh[1024];
    const int t = threadIdx.x;
    if (blockIdx.x == 0) {
        int v = (t < nb) ? bsum[t] : 0;
        sh[t] = v;
        __syncthreads();
        for (int off = 1; off < 1024; off <<= 1) {
            int add = (t >= off) ? sh[t - off] : 0;
            __syncthreads();
            sh[t] += add;
            __syncthreads();
        }
        if (t < nb) bsum[t] = sh[t] - v;
    } else {
        if (t < 16) cst[t] = cst[t] / Ef;
        __threadfence_block();
        __syncthreads();
        if (t < 4) {
            float s = 0.f;
            for (int d = 0; d < 16; ++d) s += cst[d] * cst[16 + d * 4 + t];
            cst[96 + t] = s;
        } else if (t == 4) {
            float s = 0.f;
            for (int d = 0; d < 16; ++d) s += cst[d] * cst[80 + d];
            cst[100] = s;
        }
    }
}

// scan phase 3: rowptr/cursor from hierarchical scan; fill self-loop edot entries.
__global__ void k_scan3(const int* __restrict__ excl, const int* __restrict__ bsum,
                        int* __restrict__ rowptr, int* __restrict__ cursor,
                        const float* __restrict__ cst, float4* __restrict__ edot1,
                        float* __restrict__ edot2, int N, int E, int E2) {
    int i = blockIdx.x * blockDim.x + threadIdx.x;
    if (i < N) {
        int r = excl[i] + bsum[i >> 10];
        rowptr[i] = r;
        cursor[i] = r;
        edot1[E + i] = make_float4(cst[96], cst[97], cst[98], cst[99]);
        edot2[E + i] = cst[100];
    }
    if (i == 0) rowptr[N] = E2;
}

__global__ void k_fill(const int* __restrict__ ei, int* __restrict__ cursor,
                       int* __restrict__ csr_src, int* __restrict__ csr_eid, int E, int N) {
    int e = blockIdx.x * blockDim.x + threadIdx.x;
    if (e >= E + N) return;
    int s, d;
    if (e < E) { s = ei[e]; d = ei[E + e]; }
    else       { s = d = e - E; }
    int pos = atomicAdd(&cursor[d], 1);
    csr_src[pos] = s;
    csr_eid[pos] = e;
}

// K3: h1 = x @ W1 (N x 128 @ 128 x 128), stored as bf16; fused as1/ad1.
__global__ void k_gemm1(const float* __restrict__ x, const float* __restrict__ W1,
                        const float* __restrict__ aS, const float* __restrict__ aD,
                        unsigned short* __restrict__ h1b, float* __restrict__ as1,
                        float* __restrict__ ad1, int N) {
    __shared__ float xs[4][128];
    __shared__ float red[128];
    const int j = threadIdx.x;
    const int n0 = blockIdx.x * 4;
#pragma unroll
    for (int r = 0; r < 4; ++r) {
        int nn = n0 + r;
        xs[r][j] = (nn < N) ? x[(size_t)nn * 128 + j] : 0.f;
    }
    __syncthreads();
    float acc[4] = {0.f, 0.f, 0.f, 0.f};
    for (int k = 0; k < 128; ++k) {
        float w = W1[k * 128 + j];
        acc[0] += xs[0][k] * w;
        acc[1] += xs[1][k] * w;
        acc[2] += xs[2][k] * w;
        acc[3] += xs[3][k] * w;
    }
    float asw = aS[j], adw = aD[j];
    for (int r = 0; r < 4; ++r) {
        int nn = n0 + r;
        if (nn < N) {
            h1b[(size_t)nn * 128 + j] = f2bf(acc[r]);
            red[j] = acc[r] * asw;
            __syncthreads();
            if (j < 4) {
                float s = 0.f;
                for (int c = 0; c < 32; ++c) s += red[j * 32 + c];
                as1[nn * 4 + j] = s;
            }
            __syncthreads();
            red[j] = acc[r] * adw;
            __syncthreads();
            if (j < 4) {
                float s = 0.f;
                for (int c = 0; c < 32; ++c) s += red[j * 32 + c];
                ad1[nn * 4 + j] = s;
            }
            __syncthreads();
        }
    }
}

// K6: FUSED layer-1 edge-softmax + aggregation. One wave per dst row.
// bf16 h1 gather (4 B/lane), edot1 gather (16 B, mostly L2), float4 LDS broadcast.
__global__ void k_aggr1(const int* __restrict__ rowptr, const int* __restrict__ csr_src,
                        const int* __restrict__ csr_eid, const float4* __restrict__ edot1,
                        const float* __restrict__ as1, const float* __restrict__ ad1,
                        const unsigned int* __restrict__ h1u,
                        float* __restrict__ out1, int N) {
    __shared__ float4 lds_ex4[4][64];
    __shared__ int    lds_ss[4][64];
    const int w = threadIdx.x >> 6;
    const int wid = (blockIdx.x * blockDim.x + threadIdx.x) >> 6;
    const int lane = threadIdx.x & 63;
    if (wid >= N) return;
    const int h = lane >> 4;                 // head owning channels 2*lane, 2*lane+1
    const int start = rowptr[wid], end = rowptr[wid + 1];
    const float adv0 = ad1[wid * 4 + 0], adv1 = ad1[wid * 4 + 1];
    const float adv2 = ad1[wid * 4 + 2], adv3 = ad1[wid * 4 + 3];
    float ax = 0.f, ay = 0.f, den = 0.f;
    for (int base = start; base < end; base += 64) {
        const int cnt = min(64, end - base);
        float e0 = 0.f, e1 = 0.f, e2 = 0.f, e3 = 0.f;
        int ssr = 0;
        if (lane < cnt) {
            int ee = csr_eid[base + lane];
            ssr = csr_src[base + lane];
            float4 d = edot1[ee];
            float v0 = as1[ssr * 4 + 0] + adv0 + d.x;
            float v1 = as1[ssr * 4 + 1] + adv1 + d.y;
            float v2 = as1[ssr * 4 + 2] + adv2 + d.z;
            float v3 = as1[ssr * 4 + 3] + adv3 + d.w;
            v0 = v0 > 0.f ? v0 : NEG_SLOPE * v0;
            v1 = v1 > 0.f ? v1 : NEG_SLOPE * v1;
            v2 = v2 > 0.f ? v2 : NEG_SLOPE * v2;
            v3 = v3 > 0.f ? v3 : NEG_SLOPE * v3;
            e0 = __expf(v0); e1 = __expf(v1); e2 = __expf(v2); e3 = __expf(v3);
        }
        lds_ex4[w][lane] = make_float4(e0, e1, e2, e3);
        lds_ss[w][lane] = ssr;
        for (int i = 0; i < cnt; ++i) {
            float exm = ((const float*)&lds_ex4[w][i])[h];   // 4 banks, broadcast in group
            int ss = lds_ss[w][i];
            unsigned int v = h1u[(size_t)ss * 64 + lane];
            ax += exm * __uint_as_float(v << 16);            // channel 2*lane
            ay += exm * __uint_as_float(v & 0xffff0000u);    // channel 2*lane+1
            den += exm;
        }
    }
    const float inv = 1.f / (den + 1e-16f);
    float2 r; r.x = ax * inv; r.y = ay * inv;
    *(float2*)&out1[(size_t)wid * 128 + 2 * lane] = r;
}

// K7: h2 = relu(out1 + b1) @ W2 (N x 128 @ 128 x 32); fused as2/ad2. h2 stays fp32.
__global__ void k_gemm2(const float* __restrict__ out1, const float* __restrict__ b1,
                        const float* __restrict__ W2, const float* __restrict__ aS,
                        const float* __restrict__ aD, float* __restrict__ h2,
                        float* __restrict__ as2, float* __restrict__ ad2, int N) {
    __shared__ float xs[8][128];
    const int lane = threadIdx.x & 31;
    const int r = threadIdx.x >> 5;
    const int nn = blockIdx.x * 8 + r;
    if (nn < N) {
#pragma unroll
        for (int t = 0; t < 4; ++t) {
            int k = t * 32 + lane;
            xs[r][k] = fmaxf(out1[(size_t)nn * 128 + k] + b1[k], 0.f);
        }
    }
    __syncthreads();
    if (nn < N) {
        float acc = 0.f;
        for (int k = 0; k < 128; ++k) acc += xs[r][k] * W2[k * 32 + lane];
        h2[(size_t)nn * 32 + lane] = acc;
        float vs = acc * aS[lane], vd = acc * aD[lane];
        for (int off = 16; off; off >>= 1) {
            vs += __shfl_down(vs, off, 32);
            vd += __shfl_down(vd, off, 32);
        }
        if (lane == 0) { as2[nn] = vs; ad2[nn] = vd; }
    }
}

// K10: FUSED layer-2 edge-softmax + aggregation + bias. One wave per dst row.
__global__ void k_aggr2(const int* __restrict__ rowptr, const int* __restrict__ csr_src,
                        const int* __restrict__ csr_eid, const float* __restrict__ edot2,
                        const float* __restrict__ as2, const float* __restrict__ ad2,
                        const float* __restrict__ h2, const float* __restrict__ b2,
                        float* __restrict__ out, int N) {
    __shared__ float lds_ex[4][64];
    __shared__ int   lds_ss[4][64];
    const int w = threadIdx.x >> 6;
    const int wid = (blockIdx.x * blockDim.x + threadIdx.x) >> 6;
    const int lane = threadIdx.x & 63;
    if (wid >= N) return;
    const int c = lane & 31;
    const int half = lane >> 5;
    const int start = rowptr[wid], end = rowptr[wid + 1];
    const float adv = ad2[wid];
    float acc = 0.f, den = 0.f;
    for (int base = start; base < end; base += 64) {
        const int cnt = min(64, end - base);
        float ex = 0.f;
        int ssr = 0;
        if (lane < cnt) {
            int ee = csr_eid[base + lane];
            ssr = csr_src[base + lane];
            float v = as2[ssr] + adv + edot2[ee];
            v = v > 0.f ? v : NEG_SLOPE * v;
            ex = __expf(v);
        }
        lds_ex[w][lane] = ex;
        lds_ss[w][lane] = ssr;
        for (int i = half; i < cnt; i += 2) {
            float exm = lds_ex[w][i];
            int ss = lds_ss[w][i];
            acc += exm * h2[(size_t)ss * 32 + c];
            den += exm;
        }
    }
    den += __shfl_xor(den, 32, 64);          // both halves -> total denominator
    acc += __shfl_down(acc, 32, 64);
    if (half == 0) {
        float inv = 1.f / (den + 1e-16f);
        out[(size_t)wid * 32 + c] = acc * inv + b2[c];
    }
}

extern "C" void kernel_launch(void* const* d_in, const int* in_sizes, int n_in,
                              void* d_out, int out_size, void* d_ws, size_t ws_size,
                              hipStream_t stream) {
    const float* x    = (const float*)d_in[0];
    const int*   ei   = (const int*)d_in[1];
    const float* ea   = (const float*)d_in[2];
    const float* W1   = (const float*)d_in[3];
    const float* We1  = (const float*)d_in[4];
    const float* as1w = (const float*)d_in[5];
    const float* ad1w = (const float*)d_in[6];
    const float* ae1w = (const float*)d_in[7];
    const float* b1   = (const float*)d_in[8];
    const float* W2   = (const float*)d_in[9];
    const float* We2  = (const float*)d_in[10];
    const float* as2w = (const float*)d_in[11];
    const float* ad2w = (const float*)d_in[12];
    const float* ae2w = (const float*)d_in[13];
    const float* b2   = (const float*)d_in[14];

    const int N  = in_sizes[0] / 128;
    const int E  = in_sizes[2] / 16;
    const int E2 = E + N;
    const int NB = (N + 1023) / 1024;

    float* ws = (float*)d_ws;
    size_t o = 0;
    float* cst  = ws;       o += 128;
    int* cursor = (int*)(ws + o);  o += (size_t)N;       // deg, then fill cursor
    unsigned short* h1b = (unsigned short*)(ws + o); o += (size_t)N * 64; // bf16 [N][128]; layer-2 overlays
    float* out1 = ws + o;   o += (size_t)N * 128;
    float* as1  = ws + o;   o += (size_t)N * 4;
    float* ad1  = ws + o;   o += (size_t)N * 4;
    int* rowptr = (int*)(ws + o);  o += (size_t)N + 1;
    int* csr_src = (int*)(ws + o); o += (size_t)E2;
    int* csr_eid = (int*)(ws + o); o += (size_t)E2;
    int* scan_excl = (int*)(ws + o); o += (size_t)N;
    int* scan_bsum = (int*)(ws + o); o += 1024;
    float4* edot1 = (float4*)(ws + o); o += (size_t)E2 * 4;
    float* edot2 = ws + o;  o += (size_t)E2;
    // overlay layer 2 onto h1 region (h1b dead after k_aggr1):
    // h1b region is N*64 floats-worth; h2(N*32)+as2(N)+ad2(N) = N*34 floats. fits.
    float* h2   = (float*)h1b;
    float* as2  = h2 + (size_t)N * 32;
    float* ad2  = as2 + N;

    // single contiguous zero init: cst + cursor
    hipMemsetAsync(cst, 0, (128 + (size_t)N) * sizeof(float), stream);

    k_prep0<<<1, 128, 0, stream>>>(We1, ae1w, We2, ae2w, cst);
    k_deg<<<(E + 255) / 256, 256, 0, stream>>>(ei, cursor, E);
    k_edot<<<2048, 256, 0, stream>>>(ea, cst, edot1, edot2, E);
    k_scan1<<<NB, 1024, 0, stream>>>(cursor, scan_excl, scan_bsum, N);
    k_mid<<<2, 1024, 0, stream>>>(scan_bsum, NB, cst, (float)E);
    k_scan3<<<(N + 255) / 256, 256, 0, stream>>>(scan_excl, scan_bsum, rowptr, cursor,
                                                 cst, edot1, edot2, N, E, E2);
    k_fill<<<(E2 + 255) / 256, 256, 0, stream>>>(ei, cursor, csr_src, csr_eid, E, N);

    k_gemm1<<<(N + 3) / 4, 128, 0, stream>>>(x, W1, as1w, ad1w, h1b, as1, ad1, N);
    k_aggr1<<<(N + 3) / 4, 256, 0, stream>>>(rowptr, csr_src, csr_eid, edot1,
                                             as1, ad1, (const unsigned int*)h1b, out1, N);
    k_gemm2<<<(N + 7) / 8, 256, 0, stream>>>(out1, b1, W2, as2w, ad2w, h2, as2, ad2, N);
    k_aggr2<<<(N + 3) / 4, 256, 0, stream>>>(rowptr, csr_src, csr_eid, edot2,
                                             as2, ad2, h2, b2, (float*)d_out, N);
}

// Round 17
// 422.173 us; speedup vs baseline: 1.1272x; 1.1272x over previous
//
#include <hip/hip_runtime.h>

#define NEG_SLOPE 0.2f

// round-to-nearest-even fp32 -> bf16 bits
static __device__ __forceinline__ unsigned short f2bf(float f) {
    unsigned u = __float_as_uint(f);
    u += 0x7fffu + ((u >> 16) & 1u);
    return (unsigned short)(u >> 16);
}

// K-1: weight prep (no data deps): P1[d][h] at cst[16..80), P2[d] at cst[80..96)
__global__ void k_prep0(const float* __restrict__ We1, const float* __restrict__ ae1,
                        const float* __restrict__ We2, const float* __restrict__ ae2,
                        float* __restrict__ cst) {
    int t = threadIdx.x;
    if (t < 64) {
        int d = t >> 2, h = t & 3;
        float s = 0.f;
        for (int c = 0; c < 32; ++c) s += We1[d * 128 + h * 32 + c] * ae1[h * 32 + c];
        cst[16 + t] = s;
    } else if (t < 80) {
        int d = t - 64;
        float s = 0.f;
        for (int c = 0; c < 32; ++c) s += We2[d * 32 + c] * ae2[c];
        cst[80 + d] = s;
    }
}

// K0a: dst-degree histogram ONLY (one thread per edge, one atomic; 200 KB target
// spreads contention fine — proven cheap in rounds 5-8).
__global__ void k_deg(const int* __restrict__ ei, int* __restrict__ cursor, int E) {
    int e = blockIdx.x * blockDim.x + threadIdx.x;
    if (e < E) atomicAdd(&cursor[ei[E + e]], 1);
}

// K0b: pure streaming edot precompute. Round-16 lesson: the 2048-block x 16
// same-address global atomic tail serialized ~2048-deep and dominated (85us).
// Now: P1/P2 cached in LDS; column sums leave via per-wave shuffle reduce +
// NON-ATOMIC per-block partial store to psum. No global atomics at all.
__global__ void k_edot(const float* __restrict__ ea, const float* __restrict__ cst,
                       float4* __restrict__ edot1, float* __restrict__ edot2,
                       float* __restrict__ psum, int E) {
    __shared__ float P[80];      // P1[d*4+h] at [0..64), P2[d] at [64..80)
    __shared__ float pw[4][16];
    const int tid = threadIdx.x;
    if (tid < 80) P[tid] = cst[16 + tid];
    __syncthreads();
    float loc[16];
#pragma unroll
    for (int d = 0; d < 16; ++d) loc[d] = 0.f;
    int stride = gridDim.x * blockDim.x;
    for (int e = blockIdx.x * blockDim.x + tid; e < E; e += stride) {
        const float4* eav = (const float4*)&ea[(size_t)e * 16];
        float d0 = 0.f, d1 = 0.f, d2 = 0.f, d3 = 0.f, dd = 0.f;
#pragma unroll
        for (int q = 0; q < 4; ++q) {
            float4 a = eav[q];
            loc[q * 4 + 0] += a.x; loc[q * 4 + 1] += a.y;
            loc[q * 4 + 2] += a.z; loc[q * 4 + 3] += a.w;
            d0 += a.x * P[(q * 4 + 0) * 4 + 0] + a.y * P[(q * 4 + 1) * 4 + 0]
                + a.z * P[(q * 4 + 2) * 4 + 0] + a.w * P[(q * 4 + 3) * 4 + 0];
            d1 += a.x * P[(q * 4 + 0) * 4 + 1] + a.y * P[(q * 4 + 1) * 4 + 1]
                + a.z * P[(q * 4 + 2) * 4 + 1] + a.w * P[(q * 4 + 3) * 4 + 1];
            d2 += a.x * P[(q * 4 + 0) * 4 + 2] + a.y * P[(q * 4 + 1) * 4 + 2]
                + a.z * P[(q * 4 + 2) * 4 + 2] + a.w * P[(q * 4 + 3) * 4 + 2];
            d3 += a.x * P[(q * 4 + 0) * 4 + 3] + a.y * P[(q * 4 + 1) * 4 + 3]
                + a.z * P[(q * 4 + 2) * 4 + 3] + a.w * P[(q * 4 + 3) * 4 + 3];
            dd += a.x * P[64 + q * 4 + 0] + a.y * P[64 + q * 4 + 1]
                + a.z * P[64 + q * 4 + 2] + a.w * P[64 + q * 4 + 3];
        }
        edot1[e] = make_float4(d0, d1, d2, d3);
        edot2[e] = dd;
    }
    // contention-free column-sum exit: wave butterfly -> LDS -> psum (no atomics)
    const int w = tid >> 6, lane = tid & 63;
#pragma unroll
    for (int d = 0; d < 16; ++d) {
        float v = loc[d];
        for (int off = 32; off; off >>= 1) v += __shfl_xor(v, off, 64);
        if (lane == 0) pw[w][d] = v;
    }
    __syncthreads();
    if (tid < 16) {
        psum[blockIdx.x * 16 + tid] = pw[0][tid] + pw[1][tid] + pw[2][tid] + pw[3][tid];
    }
}

// scan phase 1: block-local exclusive scan of (deg+1) [+1 = self-loop]
__global__ void k_scan1(const int* __restrict__ deg, int* __restrict__ excl,
                        int* __restrict__ bsum, int N) {
    __shared__ int sh[1024];
    const int t = threadIdx.x;
    const int i = blockIdx.x * 1024 + t;
    int v = (i < N) ? deg[i] + 1 : 0;
    sh[t] = v;
    __syncthreads();
    for (int off = 1; off < 1024; off <<= 1) {
        int add = (t >= off) ? sh[t - off] : 0;
        __syncthreads();
        sh[t] += add;
        __syncthreads();
    }
    if (i < N) excl[i] = sh[t] - v;
    if (t == 1023) bsum[blockIdx.x] = sh[1023];
}

// fused: block 0 = exclusive scan of bsum; block 1 = psum reduce -> e_mean +
// self-loop dot terms. cst: [0..16) e_mean, [16..80) P1, [80..96) P2,
// [96..100) aloop1, [100] aloop2
__global__ void k_mid(int* __restrict__ bsum, int nb, const float* __restrict__ psum,
                      int nb2, float* __restrict__ cst, float Ef) {
    __shared__ int sh[1024];
    const int t = threadIdx.x;
    if (blockIdx.x == 0) {
        int v = (t < nb) ? bsum[t] : 0;
        sh[t] = v;
        __syncthreads();
        for (int off = 1; off < 1024; off <<= 1) {
            int add = (t >= off) ? sh[t - off] : 0;
            __syncthreads();
            sh[t] += add;
            __syncthreads();
        }
        if (t < nb) bsum[t] = sh[t] - v;
    } else {
        float* shf = (float*)sh;
        const int d = t & 15, c = t >> 4;      // c in [0,64)
        float partial = 0.f;
        for (int b = c; b < nb2; b += 64) partial += psum[b * 16 + d];
        shf[t] = partial;                      // shf[c*16+d]
        __syncthreads();
        if (t < 16) {
            float s = 0.f;
            for (int c2 = 0; c2 < 64; ++c2) s += shf[c2 * 16 + t];
            cst[t] = s / Ef;                   // e_mean
        }
        __threadfence_block();
        __syncthreads();
        if (t < 4) {
            float s = 0.f;
            for (int dd = 0; dd < 16; ++dd) s += cst[dd] * cst[16 + dd * 4 + t];
            cst[96 + t] = s;
        } else if (t == 4) {
            float s = 0.f;
            for (int dd = 0; dd < 16; ++dd) s += cst[dd] * cst[80 + dd];
            cst[100] = s;
        }
    }
}

// scan phase 3: rowptr/cursor from hierarchical scan; fill self-loop edot entries.
__global__ void k_scan3(const int* __restrict__ excl, const int* __restrict__ bsum,
                        int* __restrict__ rowptr, int* __restrict__ cursor,
                        const float* __restrict__ cst, float4* __restrict__ edot1,
                        float* __restrict__ edot2, int N, int E, int E2) {
    int i = blockIdx.x * blockDim.x + threadIdx.x;
    if (i < N) {
        int r = excl[i] + bsum[i >> 10];
        rowptr[i] = r;
        cursor[i] = r;
        edot1[E + i] = make_float4(cst[96], cst[97], cst[98], cst[99]);
        edot2[E + i] = cst[100];
    }
    if (i == 0) rowptr[N] = E2;
}

__global__ void k_fill(const int* __restrict__ ei, int* __restrict__ cursor,
                       int* __restrict__ csr_src, int* __restrict__ csr_eid, int E, int N) {
    int e = blockIdx.x * blockDim.x + threadIdx.x;
    if (e >= E + N) return;
    int s, d;
    if (e < E) { s = ei[e]; d = ei[E + e]; }
    else       { s = d = e - E; }
    int pos = atomicAdd(&cursor[d], 1);
    csr_src[pos] = s;
    csr_eid[pos] = e;
}

// K3: h1 = x @ W1 (N x 128 @ 128 x 128), stored as bf16; fused as1/ad1.
__global__ void k_gemm1(const float* __restrict__ x, const float* __restrict__ W1,
                        const float* __restrict__ aS, const float* __restrict__ aD,
                        unsigned short* __restrict__ h1b, float* __restrict__ as1,
                        float* __restrict__ ad1, int N) {
    __shared__ float xs[4][128];
    __shared__ float red[128];
    const int j = threadIdx.x;
    const int n0 = blockIdx.x * 4;
#pragma unroll
    for (int r = 0; r < 4; ++r) {
        int nn = n0 + r;
        xs[r][j] = (nn < N) ? x[(size_t)nn * 128 + j] : 0.f;
    }
    __syncthreads();
    float acc[4] = {0.f, 0.f, 0.f, 0.f};
    for (int k = 0; k < 128; ++k) {
        float w = W1[k * 128 + j];
        acc[0] += xs[0][k] * w;
        acc[1] += xs[1][k] * w;
        acc[2] += xs[2][k] * w;
        acc[3] += xs[3][k] * w;
    }
    float asw = aS[j], adw = aD[j];
    for (int r = 0; r < 4; ++r) {
        int nn = n0 + r;
        if (nn < N) {
            h1b[(size_t)nn * 128 + j] = f2bf(acc[r]);
            red[j] = acc[r] * asw;
            __syncthreads();
            if (j < 4) {
                float s = 0.f;
                for (int c = 0; c < 32; ++c) s += red[j * 32 + c];
                as1[nn * 4 + j] = s;
            }
            __syncthreads();
            red[j] = acc[r] * adw;
            __syncthreads();
            if (j < 4) {
                float s = 0.f;
                for (int c = 0; c < 32; ++c) s += red[j * 32 + c];
                ad1[nn * 4 + j] = s;
            }
            __syncthreads();
        }
    }
}

// K6: FUSED layer-1 edge-softmax + aggregation. One wave per dst row.
// bf16 h1 gather (4 B/lane), edot1 gather (16 B, mostly L2), float4 LDS broadcast.
__global__ void k_aggr1(const int* __restrict__ rowptr, const int* __restrict__ csr_src,
                        const int* __restrict__ csr_eid, const float4* __restrict__ edot1,
                        const float* __restrict__ as1, const float* __restrict__ ad1,
                        const unsigned int* __restrict__ h1u,
                        float* __restrict__ out1, int N) {
    __shared__ float4 lds_ex4[4][64];
    __shared__ int    lds_ss[4][64];
    const int w = threadIdx.x >> 6;
    const int wid = (blockIdx.x * blockDim.x + threadIdx.x) >> 6;
    const int lane = threadIdx.x & 63;
    if (wid >= N) return;
    const int h = lane >> 4;                 // head owning channels 2*lane, 2*lane+1
    const int start = rowptr[wid], end = rowptr[wid + 1];
    const float adv0 = ad1[wid * 4 + 0], adv1 = ad1[wid * 4 + 1];
    const float adv2 = ad1[wid * 4 + 2], adv3 = ad1[wid * 4 + 3];
    float ax = 0.f, ay = 0.f, den = 0.f;
    for (int base = start; base < end; base += 64) {
        const int cnt = min(64, end - base);
        float e0 = 0.f, e1 = 0.f, e2 = 0.f, e3 = 0.f;
        int ssr = 0;
        if (lane < cnt) {
            int ee = csr_eid[base + lane];
            ssr = csr_src[base + lane];
            float4 d = edot1[ee];
            float v0 = as1[ssr * 4 + 0] + adv0 + d.x;
            float v1 = as1[ssr * 4 + 1] + adv1 + d.y;
            float v2 = as1[ssr * 4 + 2] + adv2 + d.z;
            float v3 = as1[ssr * 4 + 3] + adv3 + d.w;
            v0 = v0 > 0.f ? v0 : NEG_SLOPE * v0;
            v1 = v1 > 0.f ? v1 : NEG_SLOPE * v1;
            v2 = v2 > 0.f ? v2 : NEG_SLOPE * v2;
            v3 = v3 > 0.f ? v3 : NEG_SLOPE * v3;
            e0 = __expf(v0); e1 = __expf(v1); e2 = __expf(v2); e3 = __expf(v3);
        }
        lds_ex4[w][lane] = make_float4(e0, e1, e2, e3);
        lds_ss[w][lane] = ssr;
        for (int i = 0; i < cnt; ++i) {
            float exm = ((const float*)&lds_ex4[w][i])[h];   // 4 banks, broadcast in group
            int ss = lds_ss[w][i];
            unsigned int v = h1u[(size_t)ss * 64 + lane];
            ax += exm * __uint_as_float(v << 16);            // channel 2*lane
            ay += exm * __uint_as_float(v & 0xffff0000u);    // channel 2*lane+1
            den += exm;
        }
    }
    const float inv = 1.f / (den + 1e-16f);
    float2 r; r.x = ax * inv; r.y = ay * inv;
    *(float2*)&out1[(size_t)wid * 128 + 2 * lane] = r;
}

// K7: h2 = relu(out1 + b1) @ W2 (N x 128 @ 128 x 32); fused as2/ad2. h2 stays fp32.
__global__ void k_gemm2(const float* __restrict__ out1, const float* __restrict__ b1,
                        const float* __restrict__ W2, const float* __restrict__ aS,
                        const float* __restrict__ aD, float* __restrict__ h2,
                        float* __restrict__ as2, float* __restrict__ ad2, int N) {
    __shared__ float xs[8][128];
    const int lane = threadIdx.x & 31;
    const int r = threadIdx.x >> 5;
    const int nn = blockIdx.x * 8 + r;
    if (nn < N) {
#pragma unroll
        for (int t = 0; t < 4; ++t) {
            int k = t * 32 + lane;
            xs[r][k] = fmaxf(out1[(size_t)nn * 128 + k] + b1[k], 0.f);
        }
    }
    __syncthreads();
    if (nn < N) {
        float acc = 0.f;
        for (int k = 0; k < 128; ++k) acc += xs[r][k] * W2[k * 32 + lane];
        h2[(size_t)nn * 32 + lane] = acc;
        float vs = acc * aS[lane], vd = acc * aD[lane];
        for (int off = 16; off; off >>= 1) {
            vs += __shfl_down(vs, off, 32);
            vd += __shfl_down(vd, off, 32);
        }
        if (lane == 0) { as2[nn] = vs; ad2[nn] = vd; }
    }
}

// K10: FUSED layer-2 edge-softmax + aggregation + bias. One wave per dst row.
__global__ void k_aggr2(const int* __restrict__ rowptr, const int* __restrict__ csr_src,
                        const int* __restrict__ csr_eid, const float* __restrict__ edot2,
                        const float* __restrict__ as2, const float* __restrict__ ad2,
                        const float* __restrict__ h2, const float* __restrict__ b2,
                        float* __restrict__ out, int N) {
    __shared__ float lds_ex[4][64];
    __shared__ int   lds_ss[4][64];
    const int w = threadIdx.x >> 6;
    const int wid = (blockIdx.x * blockDim.x + threadIdx.x) >> 6;
    const int lane = threadIdx.x & 63;
    if (wid >= N) return;
    const int c = lane & 31;
    const int half = lane >> 5;
    const int start = rowptr[wid], end = rowptr[wid + 1];
    const float adv = ad2[wid];
    float acc = 0.f, den = 0.f;
    for (int base = start; base < end; base += 64) {
        const int cnt = min(64, end - base);
        float ex = 0.f;
        int ssr = 0;
        if (lane < cnt) {
            int ee = csr_eid[base + lane];
            ssr = csr_src[base + lane];
            float v = as2[ssr] + adv + edot2[ee];
            v = v > 0.f ? v : NEG_SLOPE * v;
            ex = __expf(v);
        }
        lds_ex[w][lane] = ex;
        lds_ss[w][lane] = ssr;
        for (int i = half; i < cnt; i += 2) {
            float exm = lds_ex[w][i];
            int ss = lds_ss[w][i];
            acc += exm * h2[(size_t)ss * 32 + c];
            den += exm;
        }
    }
    den += __shfl_xor(den, 32, 64);          // both halves -> total denominator
    acc += __shfl_down(acc, 32, 64);
    if (half == 0) {
        float inv = 1.f / (den + 1e-16f);
        out[(size_t)wid * 32 + c] = acc * inv + b2[c];
    }
}

extern "C" void kernel_launch(void* const* d_in, const int* in_sizes, int n_in,
                              void* d_out, int out_size, void* d_ws, size_t ws_size,
                              hipStream_t stream) {
    const float* x    = (const float*)d_in[0];
    const int*   ei   = (const int*)d_in[1];
    const float* ea   = (const float*)d_in[2];
    const float* W1   = (const float*)d_in[3];
    const float* We1  = (const float*)d_in[4];
    const float* as1w = (const float*)d_in[5];
    const float* ad1w = (const float*)d_in[6];
    const float* ae1w = (const float*)d_in[7];
    const float* b1   = (const float*)d_in[8];
    const float* W2   = (const float*)d_in[9];
    const float* We2  = (const float*)d_in[10];
    const float* as2w = (const float*)d_in[11];
    const float* ad2w = (const float*)d_in[12];
    const float* ae2w = (const float*)d_in[13];
    const float* b2   = (const float*)d_in[14];

    const int N  = in_sizes[0] / 128;
    const int E  = in_sizes[2] / 16;
    const int E2 = E + N;
    const int NB = (N + 1023) / 1024;
    const int NEDOT = 2048;

    float* ws = (float*)d_ws;
    size_t o = 0;
    float* cst  = ws;       o += 128;
    int* cursor = (int*)(ws + o);  o += (size_t)N;       // deg, then fill cursor
    unsigned short* h1b = (unsigned short*)(ws + o); o += (size_t)N * 64; // bf16 [N][128]; layer-2 overlays
    float* out1 = ws + o;   o += (size_t)N * 128;
    float* as1  = ws + o;   o += (size_t)N * 4;
    float* ad1  = ws + o;   o += (size_t)N * 4;
    int* rowptr = (int*)(ws + o);  o += (size_t)N + 1;
    int* csr_src = (int*)(ws + o); o += (size_t)E2;
    int* csr_eid = (int*)(ws + o); o += (size_t)E2;
    int* scan_excl = (int*)(ws + o); o += (size_t)N;
    int* scan_bsum = (int*)(ws + o); o += 1024;
    float4* edot1 = (float4*)(ws + o); o += (size_t)E2 * 4;
    float* edot2 = ws + o;  o += (size_t)E2;
    float* psum  = ws + o;  o += (size_t)NEDOT * 16;
    // overlay layer 2 onto h1 region (h1b dead after k_aggr1):
    // h1b region is N*64 floats-worth; h2(N*32)+as2(N)+ad2(N) = N*34 floats. fits.
    float* h2   = (float*)h1b;
    float* as2  = h2 + (size_t)N * 32;
    float* ad2  = as2 + N;

    // zero init: cst + cursor (cst[0..16) now fully overwritten by k_mid, harmless)
    hipMemsetAsync(cst, 0, (128 + (size_t)N) * sizeof(float), stream);

    k_prep0<<<1, 128, 0, stream>>>(We1, ae1w, We2, ae2w, cst);
    k_deg<<<(E + 255) / 256, 256, 0, stream>>>(ei, cursor, E);
    k_edot<<<NEDOT, 256, 0, stream>>>(ea, cst, edot1, edot2, psum, E);
    k_scan1<<<NB, 1024, 0, stream>>>(cursor, scan_excl, scan_bsum, N);
    k_mid<<<2, 1024, 0, stream>>>(scan_bsum, NB, psum, NEDOT, cst, (float)E);
    k_scan3<<<(N + 255) / 256, 256, 0, stream>>>(scan_excl, scan_bsum, rowptr, cursor,
                                                 cst, edot1, edot2, N, E, E2);
    k_fill<<<(E2 + 255) / 256, 256, 0, stream>>>(ei, cursor, csr_src, csr_eid, E, N);

    k_gemm1<<<(N + 3) / 4, 128, 0, stream>>>(x, W1, as1w, ad1w, h1b, as1, ad1, N);
    k_aggr1<<<(N + 3) / 4, 256, 0, stream>>>(rowptr, csr_src, csr_eid, edot1,
                                             as1, ad1, (const unsigned int*)h1b, out1, N);
    k_gemm2<<<(N + 7) / 8, 256, 0, stream>>>(out1, b1, W2, as2w, ad2w, h2, as2, ad2, N);
    k_aggr2<<<(N + 3) / 4, 256, 0, stream>>>(rowptr, csr_src, csr_eid, edot2,
                                             as2, ad2, h2, b2, (float*)d_out, N);
}

// Round 18
// 414.038 us; speedup vs baseline: 1.1493x; 1.0196x over previous
//
#include <hip/hip_runtime.h>

#define NEG_SLOPE 0.2f

// round-to-nearest-even fp32 -> bf16 bits
static __device__ __forceinline__ unsigned short f2bf(float f) {
    unsigned u = __float_as_uint(f);
    u += 0x7fffu + ((u >> 16) & 1u);
    return (unsigned short)(u >> 16);
}

// K-1: weight prep (no data deps): P1[d][h] at cst[16..80), P2[d] at cst[80..96)
__global__ void k_prep0(const float* __restrict__ We1, const float* __restrict__ ae1,
                        const float* __restrict__ We2, const float* __restrict__ ae2,
                        float* __restrict__ cst) {
    int t = threadIdx.x;
    if (t < 64) {
        int d = t >> 2, h = t & 3;
        float s = 0.f;
        for (int c = 0; c < 32; ++c) s += We1[d * 128 + h * 32 + c] * ae1[h * 32 + c];
        cst[16 + t] = s;
    } else if (t < 80) {
        int d = t - 64;
        float s = 0.f;
        for (int c = 0; c < 32; ++c) s += We2[d * 32 + c] * ae2[c];
        cst[80 + d] = s;
    }
}

// K0a: dst-degree histogram ONLY (one thread per edge, one atomic).
__global__ void k_deg(const int* __restrict__ ei, int* __restrict__ cursor, int E) {
    int e = blockIdx.x * blockDim.x + threadIdx.x;
    if (e < E) atomicAdd(&cursor[ei[E + e]], 1);
}

// K0b: pure streaming edot precompute; contention-free psum exit (round-17: 85->~20us).
__global__ void k_edot(const float* __restrict__ ea, const float* __restrict__ cst,
                       float4* __restrict__ edot1, float* __restrict__ edot2,
                       float* __restrict__ psum, int E) {
    __shared__ float P[80];      // P1[d*4+h] at [0..64), P2[d] at [64..80)
    __shared__ float pw[4][16];
    const int tid = threadIdx.x;
    if (tid < 80) P[tid] = cst[16 + tid];
    __syncthreads();
    float loc[16];
#pragma unroll
    for (int d = 0; d < 16; ++d) loc[d] = 0.f;
    int stride = gridDim.x * blockDim.x;
    for (int e = blockIdx.x * blockDim.x + tid; e < E; e += stride) {
        const float4* eav = (const float4*)&ea[(size_t)e * 16];
        float d0 = 0.f, d1 = 0.f, d2 = 0.f, d3 = 0.f, dd = 0.f;
#pragma unroll
        for (int q = 0; q < 4; ++q) {
            float4 a = eav[q];
            loc[q * 4 + 0] += a.x; loc[q * 4 + 1] += a.y;
            loc[q * 4 + 2] += a.z; loc[q * 4 + 3] += a.w;
            d0 += a.x * P[(q * 4 + 0) * 4 + 0] + a.y * P[(q * 4 + 1) * 4 + 0]
                + a.z * P[(q * 4 + 2) * 4 + 0] + a.w * P[(q * 4 + 3) * 4 + 0];
            d1 += a.x * P[(q * 4 + 0) * 4 + 1] + a.y * P[(q * 4 + 1) * 4 + 1]
                + a.z * P[(q * 4 + 2) * 4 + 1] + a.w * P[(q * 4 + 3) * 4 + 1];
            d2 += a.x * P[(q * 4 + 0) * 4 + 2] + a.y * P[(q * 4 + 1) * 4 + 2]
                + a.z * P[(q * 4 + 2) * 4 + 2] + a.w * P[(q * 4 + 3) * 4 + 2];
            d3 += a.x * P[(q * 4 + 0) * 4 + 3] + a.y * P[(q * 4 + 1) * 4 + 3]
                + a.z * P[(q * 4 + 2) * 4 + 3] + a.w * P[(q * 4 + 3) * 4 + 3];
            dd += a.x * P[64 + q * 4 + 0] + a.y * P[64 + q * 4 + 1]
                + a.z * P[64 + q * 4 + 2] + a.w * P[64 + q * 4 + 3];
        }
        edot1[e] = make_float4(d0, d1, d2, d3);
        edot2[e] = dd;
    }
    const int w = tid >> 6, lane = tid & 63;
#pragma unroll
    for (int d = 0; d < 16; ++d) {
        float v = loc[d];
        for (int off = 32; off; off >>= 1) v += __shfl_xor(v, off, 64);
        if (lane == 0) pw[w][d] = v;
    }
    __syncthreads();
    if (tid < 16) {
        psum[blockIdx.x * 16 + tid] = pw[0][tid] + pw[1][tid] + pw[2][tid] + pw[3][tid];
    }
}

// scan phase 1: block-local exclusive scan of (deg+1) [+1 = self-loop]
__global__ void k_scan1(const int* __restrict__ deg, int* __restrict__ excl,
                        int* __restrict__ bsum, int N) {
    __shared__ int sh[1024];
    const int t = threadIdx.x;
    const int i = blockIdx.x * 1024 + t;
    int v = (i < N) ? deg[i] + 1 : 0;
    sh[t] = v;
    __syncthreads();
    for (int off = 1; off < 1024; off <<= 1) {
        int add = (t >= off) ? sh[t - off] : 0;
        __syncthreads();
        sh[t] += add;
        __syncthreads();
    }
    if (i < N) excl[i] = sh[t] - v;
    if (t == 1023) bsum[blockIdx.x] = sh[1023];
}

// fused: block 0 = exclusive scan of bsum; block 1 = psum reduce -> e_mean + self-loop dots
__global__ void k_mid(int* __restrict__ bsum, int nb, const float* __restrict__ psum,
                      int nb2, float* __restrict__ cst, float Ef) {
    __shared__ int sh[1024];
    const int t = threadIdx.x;
    if (blockIdx.x == 0) {
        int v = (t < nb) ? bsum[t] : 0;
        sh[t] = v;
        __syncthreads();
        for (int off = 1; off < 1024; off <<= 1) {
            int add = (t >= off) ? sh[t - off] : 0;
            __syncthreads();
            sh[t] += add;
            __syncthreads();
        }
        if (t < nb) bsum[t] = sh[t] - v;
    } else {
        float* shf = (float*)sh;
        const int d = t & 15, c = t >> 4;      // c in [0,64)
        float partial = 0.f;
        for (int b = c; b < nb2; b += 64) partial += psum[b * 16 + d];
        shf[t] = partial;
        __syncthreads();
        if (t < 16) {
            float s = 0.f;
            for (int c2 = 0; c2 < 64; ++c2) s += shf[c2 * 16 + t];
            cst[t] = s / Ef;                   // e_mean
        }
        __threadfence_block();
        __syncthreads();
        if (t < 4) {
            float s = 0.f;
            for (int dd = 0; dd < 16; ++dd) s += cst[dd] * cst[16 + dd * 4 + t];
            cst[96 + t] = s;
        } else if (t == 4) {
            float s = 0.f;
            for (int dd = 0; dd < 16; ++dd) s += cst[dd] * cst[80 + dd];
            cst[100] = s;
        }
    }
}

// scan phase 3: rowptr/cursor from hierarchical scan; fill self-loop edot entries.
__global__ void k_scan3(const int* __restrict__ excl, const int* __restrict__ bsum,
                        int* __restrict__ rowptr, int* __restrict__ cursor,
                        const float* __restrict__ cst, float4* __restrict__ edot1,
                        float* __restrict__ edot2, int N, int E, int E2) {
    int i = blockIdx.x * blockDim.x + threadIdx.x;
    if (i < N) {
        int r = excl[i] + bsum[i >> 10];
        rowptr[i] = r;
        cursor[i] = r;
        edot1[E + i] = make_float4(cst[96], cst[97], cst[98], cst[99]);
        edot2[E + i] = cst[100];
    }
    if (i == 0) rowptr[N] = E2;
}

__global__ void k_fill(const int* __restrict__ ei, int* __restrict__ cursor,
                       int* __restrict__ csr_src, int* __restrict__ csr_eid, int E, int N) {
    int e = blockIdx.x * blockDim.x + threadIdx.x;
    if (e >= E + N) return;
    int s, d;
    if (e < E) { s = ei[e]; d = ei[E + e]; }
    else       { s = d = e - E; }
    int pos = atomicAdd(&cursor[d], 1);
    csr_src[pos] = s;
    csr_eid[pos] = e;
}

// K3: h1 = x @ W1 (N x 128 @ 128 x 128), stored as bf16; fused as1/ad1.
__global__ void k_gemm1(const float* __restrict__ x, const float* __restrict__ W1,
                        const float* __restrict__ aS, const float* __restrict__ aD,
                        unsigned short* __restrict__ h1b, float* __restrict__ as1,
                        float* __restrict__ ad1, int N) {
    __shared__ float xs[4][128];
    __shared__ float red[128];
    const int j = threadIdx.x;
    const int n0 = blockIdx.x * 4;
#pragma unroll
    for (int r = 0; r < 4; ++r) {
        int nn = n0 + r;
        xs[r][j] = (nn < N) ? x[(size_t)nn * 128 + j] : 0.f;
    }
    __syncthreads();
    float acc[4] = {0.f, 0.f, 0.f, 0.f};
    for (int k = 0; k < 128; ++k) {
        float w = W1[k * 128 + j];
        acc[0] += xs[0][k] * w;
        acc[1] += xs[1][k] * w;
        acc[2] += xs[2][k] * w;
        acc[3] += xs[3][k] * w;
    }
    float asw = aS[j], adw = aD[j];
    for (int r = 0; r < 4; ++r) {
        int nn = n0 + r;
        if (nn < N) {
            h1b[(size_t)nn * 128 + j] = f2bf(acc[r]);
            red[j] = acc[r] * asw;
            __syncthreads();
            if (j < 4) {
                float s = 0.f;
                for (int c = 0; c < 32; ++c) s += red[j * 32 + c];
                as1[nn * 4 + j] = s;
            }
            __syncthreads();
            red[j] = acc[r] * adw;
            __syncthreads();
            if (j < 4) {
                float s = 0.f;
                for (int c = 0; c < 32; ++c) s += red[j * 32 + c];
                ad1[nn * 4 + j] = s;
            }
            __syncthreads();
        }
    }
}

// K6: FUSED layer-1 edge-softmax + aggregation. One wave per dst row.
// Round-18 change: inner gather loop unrolled x4 (independent loads) — round-17
// counters showed 6 B/cy/CU effective, latency-bound at ~1-2 outstanding loads.
__global__ void k_aggr1(const int* __restrict__ rowptr, const int* __restrict__ csr_src,
                        const int* __restrict__ csr_eid, const float4* __restrict__ edot1,
                        const float* __restrict__ as1, const float* __restrict__ ad1,
                        const unsigned int* __restrict__ h1u,
                        float* __restrict__ out1, int N) {
    __shared__ float4 lds_ex4[4][64];
    __shared__ int    lds_ss[4][64];
    const int w = threadIdx.x >> 6;
    const int wid = (blockIdx.x * blockDim.x + threadIdx.x) >> 6;
    const int lane = threadIdx.x & 63;
    if (wid >= N) return;
    const int h = lane >> 4;                 // head owning channels 2*lane, 2*lane+1
    const int start = rowptr[wid], end = rowptr[wid + 1];
    const float adv0 = ad1[wid * 4 + 0], adv1 = ad1[wid * 4 + 1];
    const float adv2 = ad1[wid * 4 + 2], adv3 = ad1[wid * 4 + 3];
    float ax = 0.f, ay = 0.f, den = 0.f;
    for (int base = start; base < end; base += 64) {
        const int cnt = min(64, end - base);
        float e0 = 0.f, e1 = 0.f, e2 = 0.f, e3 = 0.f;
        int ssr = 0;
        if (lane < cnt) {
            int ee = csr_eid[base + lane];
            ssr = csr_src[base + lane];
            float4 d = edot1[ee];
            float v0 = as1[ssr * 4 + 0] + adv0 + d.x;
            float v1 = as1[ssr * 4 + 1] + adv1 + d.y;
            float v2 = as1[ssr * 4 + 2] + adv2 + d.z;
            float v3 = as1[ssr * 4 + 3] + adv3 + d.w;
            v0 = v0 > 0.f ? v0 : NEG_SLOPE * v0;
            v1 = v1 > 0.f ? v1 : NEG_SLOPE * v1;
            v2 = v2 > 0.f ? v2 : NEG_SLOPE * v2;
            v3 = v3 > 0.f ? v3 : NEG_SLOPE * v3;
            e0 = __expf(v0); e1 = __expf(v1); e2 = __expf(v2); e3 = __expf(v3);
        }
        lds_ex4[w][lane] = make_float4(e0, e1, e2, e3);
        lds_ss[w][lane] = ssr;
        int i = 0;
        for (; i + 3 < cnt; i += 4) {
            float x0 = ((const float*)&lds_ex4[w][i + 0])[h];
            float x1 = ((const float*)&lds_ex4[w][i + 1])[h];
            float x2 = ((const float*)&lds_ex4[w][i + 2])[h];
            float x3 = ((const float*)&lds_ex4[w][i + 3])[h];
            int s0 = lds_ss[w][i + 0], s1 = lds_ss[w][i + 1];
            int s2 = lds_ss[w][i + 2], s3 = lds_ss[w][i + 3];
            unsigned int v0 = h1u[(size_t)s0 * 64 + lane];
            unsigned int v1 = h1u[(size_t)s1 * 64 + lane];
            unsigned int v2 = h1u[(size_t)s2 * 64 + lane];
            unsigned int v3 = h1u[(size_t)s3 * 64 + lane];
            ax += x0 * __uint_as_float(v0 << 16) + x1 * __uint_as_float(v1 << 16)
                + x2 * __uint_as_float(v2 << 16) + x3 * __uint_as_float(v3 << 16);
            ay += x0 * __uint_as_float(v0 & 0xffff0000u) + x1 * __uint_as_float(v1 & 0xffff0000u)
                + x2 * __uint_as_float(v2 & 0xffff0000u) + x3 * __uint_as_float(v3 & 0xffff0000u);
            den += x0 + x1 + x2 + x3;
        }
        for (; i < cnt; ++i) {
            float exm = ((const float*)&lds_ex4[w][i])[h];
            int ss = lds_ss[w][i];
            unsigned int v = h1u[(size_t)ss * 64 + lane];
            ax += exm * __uint_as_float(v << 16);
            ay += exm * __uint_as_float(v & 0xffff0000u);
            den += exm;
        }
    }
    const float inv = 1.f / (den + 1e-16f);
    float2 r; r.x = ax * inv; r.y = ay * inv;
    *(float2*)&out1[(size_t)wid * 128 + 2 * lane] = r;
}

// K7: h2 = relu(out1 + b1) @ W2 (N x 128 @ 128 x 32); fused as2/ad2. h2 stays fp32.
__global__ void k_gemm2(const float* __restrict__ out1, const float* __restrict__ b1,
                        const float* __restrict__ W2, const float* __restrict__ aS,
                        const float* __restrict__ aD, float* __restrict__ h2,
                        float* __restrict__ as2, float* __restrict__ ad2, int N) {
    __shared__ float xs[8][128];
    const int lane = threadIdx.x & 31;
    const int r = threadIdx.x >> 5;
    const int nn = blockIdx.x * 8 + r;
    if (nn < N) {
#pragma unroll
        for (int t = 0; t < 4; ++t) {
            int k = t * 32 + lane;
            xs[r][k] = fmaxf(out1[(size_t)nn * 128 + k] + b1[k], 0.f);
        }
    }
    __syncthreads();
    if (nn < N) {
        float acc = 0.f;
        for (int k = 0; k < 128; ++k) acc += xs[r][k] * W2[k * 32 + lane];
        h2[(size_t)nn * 32 + lane] = acc;
        float vs = acc * aS[lane], vd = acc * aD[lane];
        for (int off = 16; off; off >>= 1) {
            vs += __shfl_down(vs, off, 32);
            vd += __shfl_down(vd, off, 32);
        }
        if (lane == 0) { as2[nn] = vs; ad2[nn] = vd; }
    }
}

// K10: FUSED layer-2 edge-softmax + aggregation + bias. One wave per dst row.
// Round-18: inner loop unrolled x4 per half (same MLP rationale as k_aggr1).
__global__ void k_aggr2(const int* __restrict__ rowptr, const int* __restrict__ csr_src,
                        const int* __restrict__ csr_eid, const float* __restrict__ edot2,
                        const float* __restrict__ as2, const float* __restrict__ ad2,
                        const float* __restrict__ h2, const float* __restrict__ b2,
                        float* __restrict__ out, int N) {
    __shared__ float lds_ex[4][64];
    __shared__ int   lds_ss[4][64];
    const int w = threadIdx.x >> 6;
    const int wid = (blockIdx.x * blockDim.x + threadIdx.x) >> 6;
    const int lane = threadIdx.x & 63;
    if (wid >= N) return;
    const int c = lane & 31;
    const int half = lane >> 5;
    const int start = rowptr[wid], end = rowptr[wid + 1];
    const float adv = ad2[wid];
    float acc = 0.f, den = 0.f;
    for (int base = start; base < end; base += 64) {
        const int cnt = min(64, end - base);
        float ex = 0.f;
        int ssr = 0;
        if (lane < cnt) {
            int ee = csr_eid[base + lane];
            ssr = csr_src[base + lane];
            float v = as2[ssr] + adv + edot2[ee];
            v = v > 0.f ? v : NEG_SLOPE * v;
            ex = __expf(v);
        }
        lds_ex[w][lane] = ex;
        lds_ss[w][lane] = ssr;
        int i = half;
        for (; i + 6 < cnt; i += 8) {
            float x0 = lds_ex[w][i + 0], x1 = lds_ex[w][i + 2];
            float x2 = lds_ex[w][i + 4], x3 = lds_ex[w][i + 6];
            int s0 = lds_ss[w][i + 0], s1 = lds_ss[w][i + 2];
            int s2 = lds_ss[w][i + 4], s3 = lds_ss[w][i + 6];
            float g0 = h2[(size_t)s0 * 32 + c];
            float g1 = h2[(size_t)s1 * 32 + c];
            float g2 = h2[(size_t)s2 * 32 + c];
            float g3 = h2[(size_t)s3 * 32 + c];
            acc += x0 * g0 + x1 * g1 + x2 * g2 + x3 * g3;
            den += x0 + x1 + x2 + x3;
        }
        for (; i < cnt; i += 2) {
            float exm = lds_ex[w][i];
            int ss = lds_ss[w][i];
            acc += exm * h2[(size_t)ss * 32 + c];
            den += exm;
        }
    }
    den += __shfl_xor(den, 32, 64);          // both halves -> total denominator
    acc += __shfl_down(acc, 32, 64);
    if (half == 0) {
        float inv = 1.f / (den + 1e-16f);
        out[(size_t)wid * 32 + c] = acc * inv + b2[c];
    }
}

extern "C" void kernel_launch(void* const* d_in, const int* in_sizes, int n_in,
                              void* d_out, int out_size, void* d_ws, size_t ws_size,
                              hipStream_t stream) {
    const float* x    = (const float*)d_in[0];
    const int*   ei   = (const int*)d_in[1];
    const float* ea   = (const float*)d_in[2];
    const float* W1   = (const float*)d_in[3];
    const float* We1  = (const float*)d_in[4];
    const float* as1w = (const float*)d_in[5];
    const float* ad1w = (const float*)d_in[6];
    const float* ae1w = (const float*)d_in[7];
    const float* b1   = (const float*)d_in[8];
    const float* W2   = (const float*)d_in[9];
    const float* We2  = (const float*)d_in[10];
    const float* as2w = (const float*)d_in[11];
    const float* ad2w = (const float*)d_in[12];
    const float* ae2w = (const float*)d_in[13];
    const float* b2   = (const float*)d_in[14];

    const int N  = in_sizes[0] / 128;
    const int E  = in_sizes[2] / 16;
    const int E2 = E + N;
    const int NB = (N + 1023) / 1024;
    const int NEDOT = 2048;

    float* ws = (float*)d_ws;
    size_t o = 0;
    float* cst  = ws;       o += 128;
    int* cursor = (int*)(ws + o);  o += (size_t)N;       // deg, then fill cursor
    unsigned short* h1b = (unsigned short*)(ws + o); o += (size_t)N * 64; // bf16 [N][128]; layer-2 overlays
    float* out1 = ws + o;   o += (size_t)N * 128;
    float* as1  = ws + o;   o += (size_t)N * 4;
    float* ad1  = ws + o;   o += (size_t)N * 4;
    int* rowptr = (int*)(ws + o);  o += (size_t)N + 1;
    int* csr_src = (int*)(ws + o); o += (size_t)E2;
    int* csr_eid = (int*)(ws + o); o += (size_t)E2;
    int* scan_excl = (int*)(ws + o); o += (size_t)N;
    int* scan_bsum = (int*)(ws + o); o += 1024;
    float4* edot1 = (float4*)(ws + o); o += (size_t)E2 * 4;
    float* edot2 = ws + o;  o += (size_t)E2;
    float* psum  = ws + o;  o += (size_t)NEDOT * 16;
    // overlay layer 2 onto h1 region (h1b dead after k_aggr1):
    // h1b region is N*64 floats-worth; h2(N*32)+as2(N)+ad2(N) = N*34 floats. fits.
    float* h2   = (float*)h1b;
    float* as2  = h2 + (size_t)N * 32;
    float* ad2  = as2 + N;

    // zero init: cst + cursor
    hipMemsetAsync(cst, 0, (128 + (size_t)N) * sizeof(float), stream);

    k_prep0<<<1, 128, 0, stream>>>(We1, ae1w, We2, ae2w, cst);
    k_deg<<<(E + 255) / 256, 256, 0, stream>>>(ei, cursor, E);
    k_edot<<<NEDOT, 256, 0, stream>>>(ea, cst, edot1, edot2, psum, E);
    k_scan1<<<NB, 1024, 0, stream>>>(cursor, scan_excl, scan_bsum, N);
    k_mid<<<2, 1024, 0, stream>>>(scan_bsum, NB, psum, NEDOT, cst, (float)E);
    k_scan3<<<(N + 255) / 256, 256, 0, stream>>>(scan_excl, scan_bsum, rowptr, cursor,
                                                 cst, edot1, edot2, N, E, E2);
    k_fill<<<(E2 + 255) / 256, 256, 0, stream>>>(ei, cursor, csr_src, csr_eid, E, N);

    k_gemm1<<<(N + 3) / 4, 128, 0, stream>>>(x, W1, as1w, ad1w, h1b, as1, ad1, N);
    k_aggr1<<<(N + 3) / 4, 256, 0, stream>>>(rowptr, csr_src, csr_eid, edot1,
                                             as1, ad1, (const unsigned int*)h1b, out1, N);
    k_gemm2<<<(N + 7) / 8, 256, 0, stream>>>(out1, b1, W2, as2w, ad2w, h2, as2, ad2, N);
    k_aggr2<<<(N + 3) / 4, 256, 0, stream>>>(rowptr, csr_src, csr_eid, edot2,
                                             as2, ad2, h2, b2, (float*)d_out, N);
}